// Round 11
// baseline (228.655 us; speedup 1.0000x reference)
//
#include <hip/hip_runtime.h>

constexpr int IN_C   = 3;
constexpr int OUT_C  = 64;
constexpr int NB     = 27;
constexpr int CR     = 4096;             // clusters per range (64 KB LDS bins)
constexpr int NS     = 16;               // point slices
constexpr int WPK_N  = 12 * 64 * 8;      // 6144 bf16 fragment elements

typedef float f32x4 __attribute__((ext_vector_type(4)));
typedef short bf16x8 __attribute__((ext_vector_type(8)));

__device__ __forceinline__ unsigned short f2bf(float f) {
    unsigned u = __builtin_bit_cast(unsigned, f);
    u += 0x7fffu + ((u >> 16) & 1u);     // round-to-nearest-even
    return (unsigned short)(u >> 16);
}
__device__ __forceinline__ float bf2f(unsigned short v) {
    return __builtin_bit_cast(float, (unsigned)v << 16);
}
__device__ __forceinline__ float bflo(unsigned u) {
    return __builtin_bit_cast(float, u << 16);
}
__device__ __forceinline__ float bfhi(unsigned u) {
    return __builtin_bit_cast(float, u & 0xffff0000u);
}

// ---- stage A (+fold in last block): range x slice LDS binning; no global atomics.
// Partial sums stored as bf16 (ushort4/bin): counts <=~30 are exact in bf16.
__global__ __launch_bounds__(256) void
k_poolscan(const int* __restrict__ cluster, const float* __restrict__ x,
           ushort4* __restrict__ partials, int N, int K, int R,
           const float* __restrict__ Wc, const float* __restrict__ Wl,
           unsigned short* __restrict__ Wpk) {
    // ---- fold block: pack W_conv @ W_lin[3:,:] into MFMA B-fragment order ----
    if (blockIdx.x >= (unsigned)(R * NS)) {
        for (int t = threadIdx.x; t < WPK_N; t += 256) {
            int j  = t & 7;
            int l  = (t >> 3) & 63;
            int st = t >> 9;
            int s  = st >> 2, tt = st & 3;
            int kk = 32 * s + 8 * (l >> 4) + j;
            int ch = 16 * tt + (l & 15);
            float acc = 0.f;
            if (kk < NB * IN_C) {
                #pragma unroll
                for (int j2 = 0; j2 < OUT_C; ++j2)
                    acc = fmaf(Wc[kk * 64 + j2], Wl[(IN_C + j2) * OUT_C + ch], acc);
            }
            Wpk[t] = f2bf(acc);
        }
        return;
    }

    __shared__ float bins[CR * 4];       // 64 KB
    const int tid = threadIdx.x;
    const int r   = blockIdx.x % R;
    const int s   = blockIdx.x / R;
    const unsigned base = (unsigned)r * CR;

    for (int i = tid; i < CR * 4; i += 256) bins[i] = 0.f;
    __syncthreads();

    const int P4 = N >> 2;               // uint4 count
    const int Q  = P4 / NS;
    const int i1 = (s == NS - 1) ? P4 : (s + 1) * Q;
    const uint4* __restrict__ cl4 = reinterpret_cast<const uint4*>(cluster);

    int i = s * Q + tid;
    uint4 c = (i < i1) ? cl4[i] : make_uint4(~0u, ~0u, ~0u, ~0u);
    while (i < i1) {
        const int inext = i + 256;
        uint4 cn = (inext < i1) ? cl4[inext] : make_uint4(~0u, ~0u, ~0u, ~0u);

        const unsigned r0 = c.x - base, r1 = c.y - base, r2 = c.z - base, r3 = c.w - base;
        const bool m0 = r0 < CR, m1 = r1 < CR, m2 = r2 < CR, m3 = r3 < CR;
        const int n = i * 4;

        float a0=0.f,a1=0.f,a2=0.f, b0=0.f,b1=0.f,b2=0.f;
        float d0=0.f,d1=0.f,d2=0.f, e0=0.f,e1=0.f,e2=0.f;
        if (m0) { a0 = x[3*n+0];  a1 = x[3*n+1];  a2 = x[3*n+2]; }
        if (m1) { b0 = x[3*n+3];  b1 = x[3*n+4];  b2 = x[3*n+5]; }
        if (m2) { d0 = x[3*n+6];  d1 = x[3*n+7];  d2 = x[3*n+8]; }
        if (m3) { e0 = x[3*n+9];  e1 = x[3*n+10]; e2 = x[3*n+11]; }

        if (m0) { atomicAdd(&bins[r0*4+0], a0); atomicAdd(&bins[r0*4+1], a1);
                  atomicAdd(&bins[r0*4+2], a2); atomicAdd(&bins[r0*4+3], 1.f); }
        if (m1) { atomicAdd(&bins[r1*4+0], b0); atomicAdd(&bins[r1*4+1], b1);
                  atomicAdd(&bins[r1*4+2], b2); atomicAdd(&bins[r1*4+3], 1.f); }
        if (m2) { atomicAdd(&bins[r2*4+0], d0); atomicAdd(&bins[r2*4+1], d1);
                  atomicAdd(&bins[r2*4+2], d2); atomicAdd(&bins[r2*4+3], 1.f); }
        if (m3) { atomicAdd(&bins[r3*4+0], e0); atomicAdd(&bins[r3*4+1], e1);
                  atomicAdd(&bins[r3*4+2], e2); atomicAdd(&bins[r3*4+3], 1.f); }

        c = cn; i = inext;
    }
    if (s == NS - 1) {
        for (int n = P4 * 4 + tid; n < N; n += 256) {
            unsigned rr = (unsigned)cluster[n] - base;
            if (rr < CR) {
                atomicAdd(&bins[rr*4+0], x[3*n+0]);
                atomicAdd(&bins[rr*4+1], x[3*n+1]);
                atomicAdd(&bins[rr*4+2], x[3*n+2]);
                atomicAdd(&bins[rr*4+3], 1.f);
            }
        }
    }
    __syncthreads();

    ushort4* __restrict__ plane = partials + (size_t)s * K;
    for (int t = tid; t < CR; t += 256) {
        int k = (int)base + t;
        if (k < K) {
            ushort4 u;
            u.x = f2bf(bins[t*4+0]); u.y = f2bf(bins[t*4+1]);
            u.z = f2bf(bins[t*4+2]); u.w = f2bf(bins[t*4+3]);
            plane[k] = u;
        }
    }
}

// ---- stage R: reduce NS bf16 planes -> pooled means; sentinel row at K ----
__global__ void k_reduce(const ushort4* __restrict__ partials, float4* __restrict__ pooled,
                         int K) {
    int k = blockIdx.x * blockDim.x + threadIdx.x;
    if (k < K) {
        float sx = 0.f, sy = 0.f, sz = 0.f, ct = 0.f;
        #pragma unroll
        for (int p = 0; p < NS; ++p) {
            ushort4 u = partials[(size_t)p * K + k];
            sx += bf2f(u.x); sy += bf2f(u.y); sz += bf2f(u.z); ct += bf2f(u.w);
        }
        float inv = 1.0f / fmaxf(ct, 1.0f);
        pooled[k] = make_float4(sx * inv, sy * inv, sz * inv, 0.f);
    } else if (k == K) {
        pooled[K] = make_float4(0.f, 0.f, 0.f, 0.f);
    }
}

// ---- stage C: MFMA conv -> bf16 v. Block = 64 clusters; wave = 16 cl x 64 ch.
// G transposed [kk][cluster]: staging writes bank=(kk+c)%32 (conflict-free),
// A-frag reads are 24 ds_read_b32 at bank=(8b+j+m)%32 -> exact 2-way (free).
__global__ __launch_bounds__(256) void
k_conv(const int* __restrict__ nb, const float4* __restrict__ pooled4,
       const unsigned short* __restrict__ Wpk, const float* __restrict__ b_lin,
       unsigned short* __restrict__ vbf, int K) {
    __shared__ float G[96][65];          // 24.96 KB, kk-major, 65-word rows
    const int tid   = threadIdx.x;
    const int cbase = blockIdx.x * 64;

    {
        const int c  = tid & 63;
        const int og = tid >> 6;                      // 0..3
        for (int kk = 81 + og; kk < 96; kk += 4) G[kk][c] = 0.f;  // zero A-pad rows
        const int kglob = min(cbase + c, K - 1);
        const int* nbrow = nb + (size_t)kglob * NB;
        for (int o = og; o < NB; o += 4) {
            unsigned s = min((unsigned)nbrow[o], (unsigned)K);  // -1 -> sentinel K
            float4 p = pooled4[s];
            G[3*o+0][c] = p.x; G[3*o+1][c] = p.y; G[3*o+2][c] = p.z;
        }
    }
    __syncthreads();

    const int lane = tid & 63;
    const int wv   = tid >> 6;           // wave -> clusters [wv*16, +16)
    const int m    = lane & 15;          // A row / D col
    const int b    = lane >> 4;          // k-block / D row group
    const int col  = wv * 16 + m;

    bf16x8 bw[12];
    const bf16x8* wp = reinterpret_cast<const bf16x8*>(Wpk);
    #pragma unroll
    for (int st = 0; st < 12; ++st) bw[st] = wp[st * 64 + lane];

    f32x4 acc[4];
    #pragma unroll
    for (int t = 0; t < 4; ++t) {
        float bb = b_lin[16 * t + m];
        acc[t] = (f32x4){bb, bb, bb, bb};
    }

    #pragma unroll
    for (int s = 0; s < 3; ++s) {
        bf16x8 af;
        #pragma unroll
        for (int j = 0; j < 8; ++j)
            af[j] = (short)f2bf(G[32 * s + 8 * b + j][col]);
        #pragma unroll
        for (int t = 0; t < 4; ++t)
            acc[t] = __builtin_amdgcn_mfma_f32_16x16x32_bf16(af, bw[s * 4 + t], acc[t], 0, 0, 0);
    }

    // D: col = lane&15, row = (lane>>4)*4 + reg
    #pragma unroll
    for (int t = 0; t < 4; ++t) {
        #pragma unroll
        for (int r = 0; r < 4; ++r) {
            int crow = cbase + wv * 16 + 4 * b + r;
            if (crow < K)
                vbf[(size_t)crow * OUT_C + 16 * t + m] = f2bf(acc[t][r]);
        }
    }
}

// ---- stage D: one-shot, 8 lanes/point. u = x @ W_lin[0:3] + v[cluster] ----
__global__ __launch_bounds__(256) void
k_point(const float* __restrict__ x, const int* __restrict__ cluster,
        const unsigned short* __restrict__ vbf, const float* __restrict__ Wl,
        float* __restrict__ out, int N) {
    const int tid = blockIdx.x * 256 + threadIdx.x;
    const int n   = tid >> 3;            // point
    const int jj  = (tid & 7) * 8;       // channel octet
    if (n >= N) return;

    const int c  = cluster[n];           // broadcast across 8 lanes
    const float x0 = x[n * 3 + 0];
    const float x1 = x[n * 3 + 1];
    const float x2 = x[n * 3 + 2];

    const float4 w0a = *reinterpret_cast<const float4*>(Wl + 0 * OUT_C + jj);
    const float4 w0b = *reinterpret_cast<const float4*>(Wl + 0 * OUT_C + jj + 4);
    const float4 w1a = *reinterpret_cast<const float4*>(Wl + 1 * OUT_C + jj);
    const float4 w1b = *reinterpret_cast<const float4*>(Wl + 1 * OUT_C + jj + 4);
    const float4 w2a = *reinterpret_cast<const float4*>(Wl + 2 * OUT_C + jj);
    const float4 w2b = *reinterpret_cast<const float4*>(Wl + 2 * OUT_C + jj + 4);

    const uint4 vr = *reinterpret_cast<const uint4*>(vbf + (size_t)c * OUT_C + jj);

    f32x4 oa, ob;
    oa[0] = fmaf(x0, w0a.x, fmaf(x1, w1a.x, fmaf(x2, w2a.x, bflo(vr.x))));
    oa[1] = fmaf(x0, w0a.y, fmaf(x1, w1a.y, fmaf(x2, w2a.y, bfhi(vr.x))));
    oa[2] = fmaf(x0, w0a.z, fmaf(x1, w1a.z, fmaf(x2, w2a.z, bflo(vr.y))));
    oa[3] = fmaf(x0, w0a.w, fmaf(x1, w1a.w, fmaf(x2, w2a.w, bfhi(vr.y))));
    ob[0] = fmaf(x0, w0b.x, fmaf(x1, w1b.x, fmaf(x2, w2b.x, bflo(vr.z))));
    ob[1] = fmaf(x0, w0b.y, fmaf(x1, w1b.y, fmaf(x2, w2b.y, bfhi(vr.z))));
    ob[2] = fmaf(x0, w0b.z, fmaf(x1, w1b.z, fmaf(x2, w2b.z, bflo(vr.w))));
    ob[3] = fmaf(x0, w0b.w, fmaf(x1, w1b.w, fmaf(x2, w2b.w, bfhi(vr.w))));

    float* op = out + (size_t)n * OUT_C + jj;
    __builtin_nontemporal_store(oa, reinterpret_cast<f32x4*>(op));
    __builtin_nontemporal_store(ob, reinterpret_cast<f32x4*>(op + 4));
}

extern "C" void kernel_launch(void* const* d_in, const int* in_sizes, int n_in,
                              void* d_out, int out_size, void* d_ws, size_t ws_size,
                              hipStream_t stream) {
    const float* x      = (const float*)d_in[0];
    const int*   cluster= (const int*)  d_in[1];
    const int*   nb     = (const int*)  d_in[2];
    const float* W_conv = (const float*)d_in[3];
    const float* W_lin  = (const float*)d_in[4];
    const float* b_lin  = (const float*)d_in[5];
    float* out = (float*)d_out;

    const int N = in_sizes[1];         // 1,000,000
    const int K = in_sizes[2] / NB;    // 200,000

    // workspace layout
    char* ws = (char*)d_ws;
    float4* pooled4 = (float4*)ws;                     // (K+1) * 16 B (sentinel at K)
    size_t off = (size_t)(K + 1) * sizeof(float4);
    off = ((off + 255) / 256) * 256;
    unsigned short* Wpk = (unsigned short*)(ws + off); // 12.3 KB packed bf16 weights
    off += ((WPK_N * sizeof(unsigned short) + 255) / 256) * 256;
    // big region: bf16 partials (NS*K*8B = 25.6 MB); after reduce consumes
    // them, vbf (K*64*2B = 25.6 MB) reuses the same region.
    ushort4* partials = (ushort4*)(ws + off);
    unsigned short* vbf = (unsigned short*)(ws + off);

    const int R = (K + CR - 1) / CR;                   // 49 ranges
    k_poolscan<<<R * NS + 1, 256, 0, stream>>>(cluster, x, partials, N, K, R,
                                               W_conv, W_lin, Wpk);
    k_reduce<<<(K + 1 + 255) / 256, 256, 0, stream>>>(partials, pooled4, K);

    const int conv_blocks = (K + 63) / 64;             // 3125
    k_conv<<<conv_blocks, 256, 0, stream>>>(nb, pooled4, Wpk, b_lin, vbf, K);

    const int point_blocks = (N * 8 + 255) / 256;      // 31250
    k_point<<<point_blocks, 256, 0, stream>>>(x, cluster, vbf, W_lin, out, N);
}

// Round 12
// 226.014 us; speedup vs baseline: 1.0117x; 1.0117x over previous
//
#include <hip/hip_runtime.h>

constexpr int IN_C   = 3;
constexpr int OUT_C  = 64;
constexpr int NB     = 27;
constexpr int CR     = 2048;             // clusters per range (32 KB LDS bins)
constexpr int NS     = 7;                // point slices; R*NS = 686 blocks (1 wave of 3/CU)
constexpr int QCAP   = 4096;             // LDS queue entries (16 KB)
constexpr int WPK_N  = 12 * 64 * 8;      // 6144 bf16 fragment elements

typedef float f32x4 __attribute__((ext_vector_type(4)));
typedef short bf16x8 __attribute__((ext_vector_type(8)));

__device__ __forceinline__ unsigned short f2bf(float f) {
    unsigned u = __builtin_bit_cast(unsigned, f);
    u += 0x7fffu + ((u >> 16) & 1u);     // round-to-nearest-even
    return (unsigned short)(u >> 16);
}
__device__ __forceinline__ float bf2f(unsigned short v) {
    return __builtin_bit_cast(float, (unsigned)v << 16);
}
__device__ __forceinline__ float bflo(unsigned u) {
    return __builtin_bit_cast(float, u << 16);
}
__device__ __forceinline__ float bfhi(unsigned u) {
    return __builtin_bit_cast(float, u & 0xffff0000u);
}

// ---- stage A (+fold in last block): queue-decoupled range binning ----
// Pass 1 streams cluster[] and appends (r<<20|n) to an LDS queue (no x access
// on the critical path). Uniform checkpoints drain the queue: independent
// x-gathers at full MLP + LDS atomics. Zero global atomics.
__global__ __launch_bounds__(256) void
k_poolscan(const int* __restrict__ cluster, const float* __restrict__ x,
           ushort4* __restrict__ partials, int N, int K, int R,
           const float* __restrict__ Wc, const float* __restrict__ Wl,
           unsigned short* __restrict__ Wpk) {
    // ---- fold block: pack W_conv @ W_lin[3:,:] into MFMA B-fragment order ----
    if (blockIdx.x >= (unsigned)(R * NS)) {
        for (int t = threadIdx.x; t < WPK_N; t += 256) {
            int j  = t & 7;
            int l  = (t >> 3) & 63;
            int st = t >> 9;
            int s  = st >> 2, tt = st & 3;
            int kk = 32 * s + 8 * (l >> 4) + j;
            int ch = 16 * tt + (l & 15);
            float acc = 0.f;
            if (kk < NB * IN_C) {
                #pragma unroll
                for (int j2 = 0; j2 < OUT_C; ++j2)
                    acc = fmaf(Wc[kk * 64 + j2], Wl[(IN_C + j2) * OUT_C + ch], acc);
            }
            Wpk[t] = f2bf(acc);
        }
        return;
    }

    __shared__ float bins[CR * 4];       // 32 KB
    __shared__ unsigned qbuf[QCAP];      // 16 KB
    __shared__ unsigned qn;
    const int tid = threadIdx.x;
    const int r   = blockIdx.x % R;
    const int s   = blockIdx.x / R;
    const unsigned base = (unsigned)r * CR;

    for (int i = tid; i < CR * 4; i += 256) bins[i] = 0.f;
    if (tid == 0) qn = 0;
    __syncthreads();

    const int P4 = N >> 2;               // uint4 count
    const int Q  = P4 / NS;
    const int i0 = s * Q;
    const int i1 = (s == NS - 1) ? P4 : (s + 1) * Q;
    const int niter = (i1 - i0 + 255) >> 8;     // uniform trip count
    const uint4* __restrict__ cl4 = reinterpret_cast<const uint4*>(cluster);

    int i = i0 + tid;
    uint4 c = (i < i1) ? cl4[i] : make_uint4(~0u, ~0u, ~0u, ~0u);

    #define APPEND(rr, nn)                                                     \
        do {                                                                   \
            unsigned _idx = atomicAdd(&qn, 1u);                                \
            if (_idx < QCAP) qbuf[_idx] = ((rr) << 20) | (unsigned)(nn);       \
            else { /* overflow: inline slow path (statistically never) */      \
                atomicAdd(&bins[(rr)*4+0], x[3*(nn)+0]);                       \
                atomicAdd(&bins[(rr)*4+1], x[3*(nn)+1]);                       \
                atomicAdd(&bins[(rr)*4+2], x[3*(nn)+2]);                       \
                atomicAdd(&bins[(rr)*4+3], 1.f);                               \
            }                                                                  \
        } while (0)

    #define DRAIN()                                                            \
        do {                                                                   \
            __syncthreads();                                                   \
            unsigned _cnt = min(qn, (unsigned)QCAP);                           \
            for (unsigned _t = tid; _t < _cnt; _t += 256) {                    \
                unsigned _u = qbuf[_t];                                        \
                unsigned _n = _u & 0xFFFFFu;                                   \
                unsigned _r = _u >> 20;                                        \
                float _x0 = x[3*_n+0], _x1 = x[3*_n+1], _x2 = x[3*_n+2];       \
                atomicAdd(&bins[_r*4+0], _x0);                                 \
                atomicAdd(&bins[_r*4+1], _x1);                                 \
                atomicAdd(&bins[_r*4+2], _x2);                                 \
                atomicAdd(&bins[_r*4+3], 1.f);                                 \
            }                                                                  \
            __syncthreads();                                                   \
            if (tid == 0) qn = 0;                                              \
            __syncthreads();                                                   \
        } while (0)

    for (int it = 0; it < niter; ++it) {
        const int inext = i + 256;
        uint4 cn = (inext < i1) ? cl4[inext] : make_uint4(~0u, ~0u, ~0u, ~0u);
        if (i < i1) {
            const int n = i * 4;
            unsigned r0 = c.x - base, r1 = c.y - base, r2 = c.z - base, r3 = c.w - base;
            if (r0 < CR) APPEND(r0, n + 0);
            if (r1 < CR) APPEND(r1, n + 1);
            if (r2 < CR) APPEND(r2, n + 2);
            if (r3 < CR) APPEND(r3, n + 3);
        }
        c = cn; i = inext;
        if ((it & 31) == 31) DRAIN();    // uniform checkpoint (all threads)
    }
    // scalar tail (N % 4), last slice only: direct atomics
    if (s == NS - 1) {
        for (int n = P4 * 4 + tid; n < N; n += 256) {
            unsigned rr = (unsigned)cluster[n] - base;
            if (rr < CR) {
                atomicAdd(&bins[rr*4+0], x[3*n+0]);
                atomicAdd(&bins[rr*4+1], x[3*n+1]);
                atomicAdd(&bins[rr*4+2], x[3*n+2]);
                atomicAdd(&bins[rr*4+3], 1.f);
            }
        }
    }
    DRAIN();                             // final drain
    #undef APPEND
    #undef DRAIN

    ushort4* __restrict__ plane = partials + (size_t)s * K;
    for (int t = tid; t < CR; t += 256) {
        int k = (int)base + t;
        if (k < K) {
            ushort4 u;
            u.x = f2bf(bins[t*4+0]); u.y = f2bf(bins[t*4+1]);
            u.z = f2bf(bins[t*4+2]); u.w = f2bf(bins[t*4+3]);
            plane[k] = u;
        }
    }
}

// ---- stage R: reduce NS bf16 planes -> pooled means; sentinel row at K ----
__global__ void k_reduce(const ushort4* __restrict__ partials, float4* __restrict__ pooled,
                         int K) {
    int k = blockIdx.x * blockDim.x + threadIdx.x;
    if (k < K) {
        float sx = 0.f, sy = 0.f, sz = 0.f, ct = 0.f;
        #pragma unroll
        for (int p = 0; p < NS; ++p) {
            ushort4 u = partials[(size_t)p * K + k];
            sx += bf2f(u.x); sy += bf2f(u.y); sz += bf2f(u.z); ct += bf2f(u.w);
        }
        float inv = 1.0f / fmaxf(ct, 1.0f);
        pooled[k] = make_float4(sx * inv, sy * inv, sz * inv, 0.f);
    } else if (k == K) {
        pooled[K] = make_float4(0.f, 0.f, 0.f, 0.f);
    }
}

// ---- stage C: MFMA conv -> bf16 v. Block = 64 clusters; wave = 16 cl x 64 ch.
// G transposed [kk][cluster]: staging writes bank=(kk+c)%32 (conflict-free),
// A-frag reads are 24 ds_read_b32 at exact 2-way (free, m136).
__global__ __launch_bounds__(256) void
k_conv(const int* __restrict__ nb, const float4* __restrict__ pooled4,
       const unsigned short* __restrict__ Wpk, const float* __restrict__ b_lin,
       unsigned short* __restrict__ vbf, int K) {
    __shared__ float G[96][65];          // 24.96 KB, kk-major, 65-word rows
    const int tid   = threadIdx.x;
    const int cbase = blockIdx.x * 64;

    {
        const int c  = tid & 63;
        const int og = tid >> 6;                      // 0..3
        for (int kk = 81 + og; kk < 96; kk += 4) G[kk][c] = 0.f;  // zero A-pad rows
        const int kglob = min(cbase + c, K - 1);
        const int* nbrow = nb + (size_t)kglob * NB;
        for (int o = og; o < NB; o += 4) {
            unsigned s = min((unsigned)nbrow[o], (unsigned)K);  // -1 -> sentinel K
            float4 p = pooled4[s];
            G[3*o+0][c] = p.x; G[3*o+1][c] = p.y; G[3*o+2][c] = p.z;
        }
    }
    __syncthreads();

    const int lane = tid & 63;
    const int wv   = tid >> 6;           // wave -> clusters [wv*16, +16)
    const int m    = lane & 15;          // A row / D col
    const int b    = lane >> 4;          // k-block / D row group
    const int col  = wv * 16 + m;

    bf16x8 bw[12];
    const bf16x8* wp = reinterpret_cast<const bf16x8*>(Wpk);
    #pragma unroll
    for (int st = 0; st < 12; ++st) bw[st] = wp[st * 64 + lane];

    f32x4 acc[4];
    #pragma unroll
    for (int t = 0; t < 4; ++t) {
        float bb = b_lin[16 * t + m];
        acc[t] = (f32x4){bb, bb, bb, bb};
    }

    #pragma unroll
    for (int s = 0; s < 3; ++s) {
        bf16x8 af;
        #pragma unroll
        for (int j = 0; j < 8; ++j)
            af[j] = (short)f2bf(G[32 * s + 8 * b + j][col]);
        #pragma unroll
        for (int t = 0; t < 4; ++t)
            acc[t] = __builtin_amdgcn_mfma_f32_16x16x32_bf16(af, bw[s * 4 + t], acc[t], 0, 0, 0);
    }

    // D: col = lane&15, row = (lane>>4)*4 + reg
    #pragma unroll
    for (int t = 0; t < 4; ++t) {
        #pragma unroll
        for (int r = 0; r < 4; ++r) {
            int crow = cbase + wv * 16 + 4 * b + r;
            if (crow < K)
                vbf[(size_t)crow * OUT_C + 16 * t + m] = f2bf(acc[t][r]);
        }
    }
}

// ---- stage D: one-shot, 8 lanes/point. u = x @ W_lin[0:3] + v[cluster] ----
__global__ __launch_bounds__(256) void
k_point(const float* __restrict__ x, const int* __restrict__ cluster,
        const unsigned short* __restrict__ vbf, const float* __restrict__ Wl,
        float* __restrict__ out, int N) {
    const int tid = blockIdx.x * 256 + threadIdx.x;
    const int n   = tid >> 3;            // point
    const int jj  = (tid & 7) * 8;       // channel octet
    if (n >= N) return;

    const int c  = cluster[n];           // broadcast across 8 lanes
    const float x0 = x[n * 3 + 0];
    const float x1 = x[n * 3 + 1];
    const float x2 = x[n * 3 + 2];

    const float4 w0a = *reinterpret_cast<const float4*>(Wl + 0 * OUT_C + jj);
    const float4 w0b = *reinterpret_cast<const float4*>(Wl + 0 * OUT_C + jj + 4);
    const float4 w1a = *reinterpret_cast<const float4*>(Wl + 1 * OUT_C + jj);
    const float4 w1b = *reinterpret_cast<const float4*>(Wl + 1 * OUT_C + jj + 4);
    const float4 w2a = *reinterpret_cast<const float4*>(Wl + 2 * OUT_C + jj);
    const float4 w2b = *reinterpret_cast<const float4*>(Wl + 2 * OUT_C + jj + 4);

    const uint4 vr = *reinterpret_cast<const uint4*>(vbf + (size_t)c * OUT_C + jj);

    f32x4 oa, ob;
    oa[0] = fmaf(x0, w0a.x, fmaf(x1, w1a.x, fmaf(x2, w2a.x, bflo(vr.x))));
    oa[1] = fmaf(x0, w0a.y, fmaf(x1, w1a.y, fmaf(x2, w2a.y, bfhi(vr.x))));
    oa[2] = fmaf(x0, w0a.z, fmaf(x1, w1a.z, fmaf(x2, w2a.z, bflo(vr.y))));
    oa[3] = fmaf(x0, w0a.w, fmaf(x1, w1a.w, fmaf(x2, w2a.w, bfhi(vr.y))));
    ob[0] = fmaf(x0, w0b.x, fmaf(x1, w1b.x, fmaf(x2, w2b.x, bflo(vr.z))));
    ob[1] = fmaf(x0, w0b.y, fmaf(x1, w1b.y, fmaf(x2, w2b.y, bfhi(vr.z))));
    ob[2] = fmaf(x0, w0b.z, fmaf(x1, w1b.z, fmaf(x2, w2b.z, bflo(vr.w))));
    ob[3] = fmaf(x0, w0b.w, fmaf(x1, w1b.w, fmaf(x2, w2b.w, bfhi(vr.w))));

    float* op = out + (size_t)n * OUT_C + jj;
    __builtin_nontemporal_store(oa, reinterpret_cast<f32x4*>(op));
    __builtin_nontemporal_store(ob, reinterpret_cast<f32x4*>(op + 4));
}

extern "C" void kernel_launch(void* const* d_in, const int* in_sizes, int n_in,
                              void* d_out, int out_size, void* d_ws, size_t ws_size,
                              hipStream_t stream) {
    const float* x      = (const float*)d_in[0];
    const int*   cluster= (const int*)  d_in[1];
    const int*   nb     = (const int*)  d_in[2];
    const float* W_conv = (const float*)d_in[3];
    const float* W_lin  = (const float*)d_in[4];
    const float* b_lin  = (const float*)d_in[5];
    float* out = (float*)d_out;

    const int N = in_sizes[1];         // 1,000,000
    const int K = in_sizes[2] / NB;    // 200,000

    // workspace layout
    char* ws = (char*)d_ws;
    float4* pooled4 = (float4*)ws;                     // (K+1) * 16 B (sentinel at K)
    size_t off = (size_t)(K + 1) * sizeof(float4);
    off = ((off + 255) / 256) * 256;
    unsigned short* Wpk = (unsigned short*)(ws + off); // 12.3 KB packed bf16 weights
    off += ((WPK_N * sizeof(unsigned short) + 255) / 256) * 256;
    // big region: bf16 partials (NS*K*8B = 11.2 MB); after reduce consumes
    // them, vbf (K*64*2B = 25.6 MB) reuses the same region.
    ushort4* partials = (ushort4*)(ws + off);
    unsigned short* vbf = (unsigned short*)(ws + off);

    const int R = (K + CR - 1) / CR;                   // 98 ranges
    k_poolscan<<<R * NS + 1, 256, 0, stream>>>(cluster, x, partials, N, K, R,
                                               W_conv, W_lin, Wpk);
    k_reduce<<<(K + 1 + 255) / 256, 256, 0, stream>>>(partials, pooled4, K);

    const int conv_blocks = (K + 63) / 64;             // 3125
    k_conv<<<conv_blocks, 256, 0, stream>>>(nb, pooled4, Wpk, b_lin, vbf, K);

    const int point_blocks = (N * 8 + 255) / 256;      // 31250
    k_point<<<point_blocks, 256, 0, stream>>>(x, cluster, vbf, W_lin, out, N);
}

// Round 13
// 175.065 us; speedup vs baseline: 1.3061x; 1.2910x over previous
//
#include <hip/hip_runtime.h>

constexpr int IN_C   = 3;
constexpr int OUT_C  = 64;
constexpr int NB     = 27;
constexpr int CR     = 8192;             // clusters per range (128 KB LDS bins)
constexpr int NS     = 10;               // point slices; R*NS = 250 blocks (1/CU, one round)
constexpr int QCAP   = 3072;             // LDS queue entries (12 KB)
constexpr int WPK_N  = 12 * 64 * 8;      // 6144 bf16 fragment elements

typedef float f32x4 __attribute__((ext_vector_type(4)));
typedef short bf16x8 __attribute__((ext_vector_type(8)));

__device__ __forceinline__ unsigned short f2bf(float f) {
    unsigned u = __builtin_bit_cast(unsigned, f);
    u += 0x7fffu + ((u >> 16) & 1u);     // round-to-nearest-even
    return (unsigned short)(u >> 16);
}
__device__ __forceinline__ float bf2f(unsigned short v) {
    return __builtin_bit_cast(float, (unsigned)v << 16);
}
__device__ __forceinline__ float bflo(unsigned u) {
    return __builtin_bit_cast(float, u << 16);
}
__device__ __forceinline__ float bfhi(unsigned u) {
    return __builtin_bit_cast(float, u & 0xffff0000u);
}

// ---- stage A (+fold in last block): queue-decoupled range binning ----
// CR=8192 -> R=25: total redundant cluster stream is only 25 x 4MB = 100MB
// (vs 392MB at CR=2048). Pass 1 appends point indices to an LDS queue (no x
// access on the critical path); uniform checkpoints drain with independent
// x-gathers at full MLP. Zero global atomics.
__global__ __launch_bounds__(512) void
k_poolscan(const int* __restrict__ cluster, const float* __restrict__ x,
           ushort4* __restrict__ partials, int N, int K, int R,
           const float* __restrict__ Wc, const float* __restrict__ Wl,
           unsigned short* __restrict__ Wpk) {
    // ---- fold block: pack W_conv @ W_lin[3:,:] into MFMA B-fragment order ----
    if (blockIdx.x >= (unsigned)(R * NS)) {
        for (int t = threadIdx.x; t < WPK_N; t += 512) {
            int j  = t & 7;
            int l  = (t >> 3) & 63;
            int st = t >> 9;
            int s  = st >> 2, tt = st & 3;
            int kk = 32 * s + 8 * (l >> 4) + j;
            int ch = 16 * tt + (l & 15);
            float acc = 0.f;
            if (kk < NB * IN_C) {
                #pragma unroll
                for (int j2 = 0; j2 < OUT_C; ++j2)
                    acc = fmaf(Wc[kk * 64 + j2], Wl[(IN_C + j2) * OUT_C + ch], acc);
            }
            Wpk[t] = f2bf(acc);
        }
        return;
    }

    __shared__ float bins[CR * 4];       // 128 KB
    __shared__ unsigned qbuf[QCAP];      // 12 KB (stores point index n)
    __shared__ unsigned qn;
    const int tid = threadIdx.x;
    const int r   = blockIdx.x % R;
    const int s   = blockIdx.x / R;
    const unsigned base = (unsigned)r * CR;

    for (int i = tid; i < CR * 4; i += 512) bins[i] = 0.f;
    if (tid == 0) qn = 0;
    __syncthreads();

    const int P4 = N >> 2;               // uint4 count
    const int Q  = P4 / NS;
    const int i0 = s * Q;
    const int i1 = (s == NS - 1) ? P4 : (s + 1) * Q;
    const int niter = (i1 - i0 + 511) >> 9;     // uniform trip count
    const uint4* __restrict__ cl4 = reinterpret_cast<const uint4*>(cluster);

    int i = i0 + tid;
    uint4 c = (i < i1) ? cl4[i] : make_uint4(~0u, ~0u, ~0u, ~0u);

    #define APPEND(rr, nn)                                                     \
        do {                                                                   \
            unsigned _idx = atomicAdd(&qn, 1u);                                \
            if (_idx < QCAP) qbuf[_idx] = (unsigned)(nn);                      \
            else { /* overflow: inline slow path (statistically never) */      \
                atomicAdd(&bins[(rr)*4+0], x[3*(nn)+0]);                       \
                atomicAdd(&bins[(rr)*4+1], x[3*(nn)+1]);                       \
                atomicAdd(&bins[(rr)*4+2], x[3*(nn)+2]);                       \
                atomicAdd(&bins[(rr)*4+3], 1.f);                               \
            }                                                                  \
        } while (0)

    #define DRAIN()                                                            \
        do {                                                                   \
            __syncthreads();                                                   \
            unsigned _cnt = min(qn, (unsigned)QCAP);                           \
            for (unsigned _t = tid; _t < _cnt; _t += 512) {                    \
                unsigned _n = qbuf[_t];                                        \
                unsigned _r = (unsigned)cluster[_n] - base;  /* L2-hot */      \
                float _x0 = x[3*_n+0], _x1 = x[3*_n+1], _x2 = x[3*_n+2];       \
                atomicAdd(&bins[_r*4+0], _x0);                                 \
                atomicAdd(&bins[_r*4+1], _x1);                                 \
                atomicAdd(&bins[_r*4+2], _x2);                                 \
                atomicAdd(&bins[_r*4+3], 1.f);                                 \
            }                                                                  \
            __syncthreads();                                                   \
            if (tid == 0) qn = 0;                                              \
            __syncthreads();                                                   \
        } while (0)

    for (int it = 0; it < niter; ++it) {
        const int inext = i + 512;
        uint4 cn = (inext < i1) ? cl4[inext] : make_uint4(~0u, ~0u, ~0u, ~0u);
        if (i < i1) {
            const int n = i * 4;
            unsigned r0 = c.x - base, r1 = c.y - base, r2 = c.z - base, r3 = c.w - base;
            if (r0 < CR) APPEND(r0, n + 0);
            if (r1 < CR) APPEND(r1, n + 1);
            if (r2 < CR) APPEND(r2, n + 2);
            if (r3 < CR) APPEND(r3, n + 3);
        }
        c = cn; i = inext;
        if ((it & 15) == 15) DRAIN();    // uniform checkpoint (all threads)
    }
    // scalar tail (N % 4), last slice only: direct atomics
    if (s == NS - 1) {
        for (int n = P4 * 4 + tid; n < N; n += 512) {
            unsigned rr = (unsigned)cluster[n] - base;
            if (rr < CR) {
                atomicAdd(&bins[rr*4+0], x[3*n+0]);
                atomicAdd(&bins[rr*4+1], x[3*n+1]);
                atomicAdd(&bins[rr*4+2], x[3*n+2]);
                atomicAdd(&bins[rr*4+3], 1.f);
            }
        }
    }
    DRAIN();                             // final drain
    #undef APPEND
    #undef DRAIN

    ushort4* __restrict__ plane = partials + (size_t)s * K;
    for (int t = tid; t < CR; t += 512) {
        int k = (int)base + t;
        if (k < K) {
            ushort4 u;
            u.x = f2bf(bins[t*4+0]); u.y = f2bf(bins[t*4+1]);
            u.z = f2bf(bins[t*4+2]); u.w = f2bf(bins[t*4+3]);
            plane[k] = u;
        }
    }
}

// ---- stage R: reduce NS bf16 planes -> pooled means; sentinel row at K ----
__global__ void k_reduce(const ushort4* __restrict__ partials, float4* __restrict__ pooled,
                         int K) {
    int k = blockIdx.x * blockDim.x + threadIdx.x;
    if (k < K) {
        float sx = 0.f, sy = 0.f, sz = 0.f, ct = 0.f;
        #pragma unroll
        for (int p = 0; p < NS; ++p) {
            ushort4 u = partials[(size_t)p * K + k];
            sx += bf2f(u.x); sy += bf2f(u.y); sz += bf2f(u.z); ct += bf2f(u.w);
        }
        float inv = 1.0f / fmaxf(ct, 1.0f);
        pooled[k] = make_float4(sx * inv, sy * inv, sz * inv, 0.f);
    } else if (k == K) {
        pooled[K] = make_float4(0.f, 0.f, 0.f, 0.f);
    }
}

// ---- stage C: MFMA conv -> bf16 v. Block = 64 clusters; wave = 16 cl x 64 ch.
// G transposed [kk][cluster]: staging writes bank=(kk+c)%32 (conflict-free),
// A-frag reads are 24 ds_read_b32 at exact 2-way (free, m136).
__global__ __launch_bounds__(256) void
k_conv(const int* __restrict__ nb, const float4* __restrict__ pooled4,
       const unsigned short* __restrict__ Wpk, const float* __restrict__ b_lin,
       unsigned short* __restrict__ vbf, int K) {
    __shared__ float G[96][65];          // 24.96 KB, kk-major, 65-word rows
    const int tid   = threadIdx.x;
    const int cbase = blockIdx.x * 64;

    {
        const int c  = tid & 63;
        const int og = tid >> 6;                      // 0..3
        for (int kk = 81 + og; kk < 96; kk += 4) G[kk][c] = 0.f;  // zero A-pad rows
        const int kglob = min(cbase + c, K - 1);
        const int* nbrow = nb + (size_t)kglob * NB;
        for (int o = og; o < NB; o += 4) {
            unsigned s = min((unsigned)nbrow[o], (unsigned)K);  // -1 -> sentinel K
            float4 p = pooled4[s];
            G[3*o+0][c] = p.x; G[3*o+1][c] = p.y; G[3*o+2][c] = p.z;
        }
    }
    __syncthreads();

    const int lane = tid & 63;
    const int wv   = tid >> 6;           // wave -> clusters [wv*16, +16)
    const int m    = lane & 15;          // A row / D col
    const int b    = lane >> 4;          // k-block / D row group
    const int col  = wv * 16 + m;

    bf16x8 bw[12];
    const bf16x8* wp = reinterpret_cast<const bf16x8*>(Wpk);
    #pragma unroll
    for (int st = 0; st < 12; ++st) bw[st] = wp[st * 64 + lane];

    f32x4 acc[4];
    #pragma unroll
    for (int t = 0; t < 4; ++t) {
        float bb = b_lin[16 * t + m];
        acc[t] = (f32x4){bb, bb, bb, bb};
    }

    #pragma unroll
    for (int s = 0; s < 3; ++s) {
        bf16x8 af;
        #pragma unroll
        for (int j = 0; j < 8; ++j)
            af[j] = (short)f2bf(G[32 * s + 8 * b + j][col]);
        #pragma unroll
        for (int t = 0; t < 4; ++t)
            acc[t] = __builtin_amdgcn_mfma_f32_16x16x32_bf16(af, bw[s * 4 + t], acc[t], 0, 0, 0);
    }

    // D: col = lane&15, row = (lane>>4)*4 + reg
    #pragma unroll
    for (int t = 0; t < 4; ++t) {
        #pragma unroll
        for (int r = 0; r < 4; ++r) {
            int crow = cbase + wv * 16 + 4 * b + r;
            if (crow < K)
                vbf[(size_t)crow * OUT_C + 16 * t + m] = f2bf(acc[t][r]);
        }
    }
}

// ---- stage D: one-shot, 8 lanes/point. u = x @ W_lin[0:3] + v[cluster] ----
__global__ __launch_bounds__(256) void
k_point(const float* __restrict__ x, const int* __restrict__ cluster,
        const unsigned short* __restrict__ vbf, const float* __restrict__ Wl,
        float* __restrict__ out, int N) {
    const int tid = blockIdx.x * 256 + threadIdx.x;
    const int n   = tid >> 3;            // point
    const int jj  = (tid & 7) * 8;       // channel octet
    if (n >= N) return;

    const int c  = cluster[n];           // broadcast across 8 lanes
    const float x0 = x[n * 3 + 0];
    const float x1 = x[n * 3 + 1];
    const float x2 = x[n * 3 + 2];

    const float4 w0a = *reinterpret_cast<const float4*>(Wl + 0 * OUT_C + jj);
    const float4 w0b = *reinterpret_cast<const float4*>(Wl + 0 * OUT_C + jj + 4);
    const float4 w1a = *reinterpret_cast<const float4*>(Wl + 1 * OUT_C + jj);
    const float4 w1b = *reinterpret_cast<const float4*>(Wl + 1 * OUT_C + jj + 4);
    const float4 w2a = *reinterpret_cast<const float4*>(Wl + 2 * OUT_C + jj);
    const float4 w2b = *reinterpret_cast<const float4*>(Wl + 2 * OUT_C + jj + 4);

    const uint4 vr = *reinterpret_cast<const uint4*>(vbf + (size_t)c * OUT_C + jj);

    f32x4 oa, ob;
    oa[0] = fmaf(x0, w0a.x, fmaf(x1, w1a.x, fmaf(x2, w2a.x, bflo(vr.x))));
    oa[1] = fmaf(x0, w0a.y, fmaf(x1, w1a.y, fmaf(x2, w2a.y, bfhi(vr.x))));
    oa[2] = fmaf(x0, w0a.z, fmaf(x1, w1a.z, fmaf(x2, w2a.z, bflo(vr.y))));
    oa[3] = fmaf(x0, w0a.w, fmaf(x1, w1a.w, fmaf(x2, w2a.w, bfhi(vr.y))));
    ob[0] = fmaf(x0, w0b.x, fmaf(x1, w1b.x, fmaf(x2, w2b.x, bflo(vr.z))));
    ob[1] = fmaf(x0, w0b.y, fmaf(x1, w1b.y, fmaf(x2, w2b.y, bfhi(vr.z))));
    ob[2] = fmaf(x0, w0b.z, fmaf(x1, w1b.z, fmaf(x2, w2b.z, bflo(vr.w))));
    ob[3] = fmaf(x0, w0b.w, fmaf(x1, w1b.w, fmaf(x2, w2b.w, bfhi(vr.w))));

    float* op = out + (size_t)n * OUT_C + jj;
    __builtin_nontemporal_store(oa, reinterpret_cast<f32x4*>(op));
    __builtin_nontemporal_store(ob, reinterpret_cast<f32x4*>(op + 4));
}

extern "C" void kernel_launch(void* const* d_in, const int* in_sizes, int n_in,
                              void* d_out, int out_size, void* d_ws, size_t ws_size,
                              hipStream_t stream) {
    const float* x      = (const float*)d_in[0];
    const int*   cluster= (const int*)  d_in[1];
    const int*   nb     = (const int*)  d_in[2];
    const float* W_conv = (const float*)d_in[3];
    const float* W_lin  = (const float*)d_in[4];
    const float* b_lin  = (const float*)d_in[5];
    float* out = (float*)d_out;

    const int N = in_sizes[1];         // 1,000,000
    const int K = in_sizes[2] / NB;    // 200,000

    // workspace layout
    char* ws = (char*)d_ws;
    float4* pooled4 = (float4*)ws;                     // (K+1) * 16 B (sentinel at K)
    size_t off = (size_t)(K + 1) * sizeof(float4);
    off = ((off + 255) / 256) * 256;
    unsigned short* Wpk = (unsigned short*)(ws + off); // 12.3 KB packed bf16 weights
    off += ((WPK_N * sizeof(unsigned short) + 255) / 256) * 256;
    // big region: bf16 partials (NS*K*8B = 16 MB); after reduce consumes
    // them, vbf (K*64*2B = 25.6 MB) reuses the same region.
    ushort4* partials = (ushort4*)(ws + off);
    unsigned short* vbf = (unsigned short*)(ws + off);

    const int R = (K + CR - 1) / CR;                   // 25 ranges
    k_poolscan<<<R * NS + 1, 512, 0, stream>>>(cluster, x, partials, N, K, R,
                                               W_conv, W_lin, Wpk);
    k_reduce<<<(K + 1 + 255) / 256, 256, 0, stream>>>(partials, pooled4, K);

    const int conv_blocks = (K + 63) / 64;             // 3125
    k_conv<<<conv_blocks, 256, 0, stream>>>(nb, pooled4, Wpk, b_lin, vbf, K);

    const int point_blocks = (N * 8 + 255) / 256;      // 31250
    k_point<<<point_blocks, 256, 0, stream>>>(x, cluster, vbf, W_lin, out, N);
}